// Round 1
// baseline (854.407 us; speedup 1.0000x reference)
//
#include <hip/hip_runtime.h>
#include <math.h>

#define N_NODES   50000
#define N_EDGES   1600000
#define E_TOT     (N_EDGES + N_NODES)
#define N_FEAT    128
#define NODE_EMB  64
#define HIDDEN    64
#define N_GRAPHS  128
#define NEG_SLOPE 0.2f

// ---- monotone float<->uint encoding for atomicMax on floats ----
__device__ __forceinline__ unsigned fenc(float f) {
    unsigned u = __float_as_uint(f);
    return (u & 0x80000000u) ? ~u : (u | 0x80000000u);
}
__device__ __forceinline__ float fdec(unsigned k) {
    unsigned u = (k & 0x80000000u) ? (k & 0x7FFFFFFFu) : ~k;
    return __uint_as_float(u);
}

// ---- zero a u32 buffer ----
__global__ void zero_u32(unsigned* p, int n) {
    int i = blockIdx.x * 256 + threadIdx.x;
    if (i < n) p[i] = 0u;
}

// ---- node embedding MLP: h = relu(x@w1+b1)@w2+b2 ; wave per node ----
__global__ __launch_bounds__(256) void node_mlp(
    const float* __restrict__ x,
    const float* __restrict__ w1, const float* __restrict__ b1,
    const float* __restrict__ w2, const float* __restrict__ b2,
    float* __restrict__ out)
{
    int lane = threadIdx.x & 63;
    int n = blockIdx.x * 4 + (threadIdx.x >> 6);
    if (n >= N_NODES) return;
    const float* xr = x + (size_t)n * N_FEAT;
    float acc = b1[lane];
#pragma unroll 8
    for (int k = 0; k < N_FEAT; ++k)
        acc = fmaf(xr[k], w1[k * NODE_EMB + lane], acc);
    float h = fmaxf(acc, 0.f);
    float acc2 = b2[lane];
#pragma unroll 8
    for (int k = 0; k < NODE_EMB; ++k)
        acc2 = fmaf(__shfl(h, k, 64), w2[k * NODE_EMB + lane], acc2);
    out[(size_t)n * NODE_EMB + lane] = acc2;
}

// ---- per-layer linear: hlin = hin@W ; asrc[n]=hlin.a_src ; adst[n]=hlin.a_dst ----
__global__ __launch_bounds__(256) void gemm_alpha(
    const float* __restrict__ hin, const float* __restrict__ W,
    const float* __restrict__ av_src, const float* __restrict__ av_dst,
    float* __restrict__ hlin, float* __restrict__ asrc, float* __restrict__ adst)
{
    int lane = threadIdx.x & 63;
    int n = blockIdx.x * 4 + (threadIdx.x >> 6);
    if (n >= N_NODES) return;
    const float* hr = hin + (size_t)n * 64;
    float acc = 0.f;
#pragma unroll 8
    for (int k = 0; k < 64; ++k)
        acc = fmaf(hr[k], W[k * 64 + lane], acc);
    hlin[(size_t)n * 64 + lane] = acc;
    float ps = acc * av_src[lane];
    float pd = acc * av_dst[lane];
#pragma unroll
    for (int off = 32; off; off >>= 1) {
        ps += __shfl_xor(ps, off, 64);
        pd += __shfl_xor(pd, off, 64);
    }
    if (lane == 0) { asrc[n] = ps; adst[n] = pd; }
}

// ---- CSR build: count incoming edges per dst ----
__global__ void count_dst(const int* __restrict__ ei, unsigned* __restrict__ counts) {
    int e = blockIdx.x * 256 + threadIdx.x;
    if (e >= E_TOT) return;
    int dst = (e < N_EDGES) ? ei[N_EDGES + e] : (e - N_EDGES);
    atomicAdd(&counts[dst], 1u);
}

// ---- single-block exclusive scan of counts -> row_ptr, cursor ----
__global__ __launch_bounds__(1024) void scan_counts(
    const unsigned* __restrict__ counts,
    unsigned* __restrict__ row_ptr, unsigned* __restrict__ cursor)
{
    __shared__ unsigned wtot[16];
    __shared__ unsigned woff[16];
    __shared__ unsigned carry_s;
    int tid = threadIdx.x, lane = tid & 63, wid = tid >> 6;
    if (tid == 0) carry_s = 0u;
    __syncthreads();
    for (int base = 0; base < N_NODES; base += 1024) {
        unsigned c = carry_s;
        int i = base + tid;
        unsigned v = (i < N_NODES) ? counts[i] : 0u;
        unsigned xs = v;
#pragma unroll
        for (int off = 1; off < 64; off <<= 1) {
            unsigned t = __shfl_up(xs, off, 64);
            if (lane >= off) xs += t;
        }
        if (lane == 63) wtot[wid] = xs;
        __syncthreads();
        if (tid == 0) {
            unsigned run = 0;
            for (int w = 0; w < 16; ++w) { woff[w] = run; run += wtot[w]; }
            carry_s = c + run;
        }
        __syncthreads();
        if (i < N_NODES) {
            unsigned ex = c + woff[wid] + xs - v;
            row_ptr[i] = ex;
            cursor[i]  = ex;
        }
    }
    __syncthreads();
    if (tid == 0) row_ptr[N_NODES] = carry_s;
}

// ---- CSR fill: scatter src ids grouped by dst ----
__global__ void fill_csr(const int* __restrict__ ei,
                         unsigned* __restrict__ cursor, int* __restrict__ csr_src) {
    int e = blockIdx.x * 256 + threadIdx.x;
    if (e >= E_TOT) return;
    int src, dst;
    if (e < N_EDGES) { src = ei[e]; dst = ei[N_EDGES + e]; }
    else             { src = dst = e - N_EDGES; }
    unsigned pos = atomicAdd(&cursor[dst], 1u);
    csr_src[pos] = src;
}

// ---- GAT aggregation: wave per dst node; softmax over incoming edges ----
template <int RELU>
__global__ __launch_bounds__(256) void gat_agg(
    const float* __restrict__ hlin,
    const float* __restrict__ asrc, const float* __restrict__ adst,
    const unsigned* __restrict__ row_ptr, const int* __restrict__ csr_src,
    const float* __restrict__ bias, float* __restrict__ out)
{
    int lane = threadIdx.x & 63;
    int d = blockIdx.x * 4 + (threadIdx.x >> 6);
    if (d >= N_NODES) return;
    int s0 = (int)row_ptr[d], s1 = (int)row_ptr[d + 1];
    float ad = adst[d];

    // phase 1: online softmax stats, lanes stride over edges
    float m = -INFINITY, s = 0.f;
    for (int i = s0 + lane; i < s1; i += 64) {
        int sn = csr_src[i];
        float e = asrc[sn] + ad;
        e = (e >= 0.f) ? e : NEG_SLOPE * e;
        float mn = fmaxf(m, e);
        s = s * __expf(m - mn) + __expf(e - mn);
        m = mn;
    }
    float M = m;
#pragma unroll
    for (int off = 32; off; off >>= 1) M = fmaxf(M, __shfl_xor(M, off, 64));
    float sp = (m == -INFINITY) ? 0.f : s * __expf(m - M);
#pragma unroll
    for (int off = 32; off; off >>= 1) sp += __shfl_xor(sp, off, 64);
    float inv = 1.f / (sp + 1e-16f);

    // phase 2: weighted aggregation, lane = feature index
    float acc = 0.f;
    for (int i = s0; i < s1; ++i) {
        int sn = csr_src[i];
        float e = asrc[sn] + ad;
        e = (e >= 0.f) ? e : NEG_SLOPE * e;
        float al = __expf(e - M) * inv;
        acc = fmaf(al, hlin[(size_t)sn * 64 + lane], acc);
    }
    acc += bias[lane];
    if (RELU) acc = fmaxf(acc, 0.f);
    out[(size_t)d * 64 + lane] = acc;
}

// ---- global max pool init ----
__global__ void pool_init(unsigned* g_enc) {
    int i = blockIdx.x * 256 + threadIdx.x;
    if (i < N_GRAPHS * HIDDEN) g_enc[i] = fenc(-INFINITY);
}

// ---- global max pool: wave per node, lane = feature ----
__global__ __launch_bounds__(256) void pool_max(
    const float* __restrict__ h, const int* __restrict__ batch,
    unsigned* __restrict__ g_enc)
{
    int lane = threadIdx.x & 63;
    int n = blockIdx.x * 4 + (threadIdx.x >> 6);
    if (n >= N_NODES) return;
    int g = batch[n];
    atomicMax(&g_enc[g * HIDDEN + lane], fenc(h[(size_t)n * HIDDEN + lane]));
}

// ---- readout MLP: one block, thread per graph ----
__global__ __launch_bounds__(128) void readout(
    const unsigned* __restrict__ g_enc,
    const float* __restrict__ fc1w, const float* __restrict__ fc1b,
    const float* __restrict__ fc2w, const float* __restrict__ fc2b,
    float* __restrict__ out)
{
    __shared__ float g[N_GRAPHS * HIDDEN];
    for (int i = threadIdx.x; i < N_GRAPHS * HIDDEN; i += 128)
        g[i] = fdec(g_enc[i]);
    __syncthreads();
    int gi = threadIdx.x;
    float o = fc2b[0];
    for (int j = 0; j < HIDDEN; ++j) {
        float a = fc1b[j];
#pragma unroll 8
        for (int k = 0; k < HIDDEN; ++k)
            a = fmaf(g[gi * HIDDEN + k], fc1w[k * HIDDEN + j], a);
        o = fmaf(fmaxf(a, 0.f), fc2w[j], o);
    }
    out[gi] = o;
}

extern "C" void kernel_launch(void* const* d_in, const int* in_sizes, int n_in,
                              void* d_out, int out_size, void* d_ws, size_t ws_size,
                              hipStream_t stream)
{
    const float* x      = (const float*)d_in[0];
    const int*   ei     = (const int*)d_in[1];
    // d_in[2] edge_attr: dead value in reference, never read
    const int*   batch  = (const int*)d_in[3];
    const float* n_w1   = (const float*)d_in[4];
    const float* n_b1   = (const float*)d_in[5];
    const float* n_w2   = (const float*)d_in[6];
    const float* n_b2   = (const float*)d_in[7];
    // d_in[8..11] edge MLP weights: dead
    const float* c1_w    = (const float*)d_in[12];
    const float* c1_asrc = (const float*)d_in[13];
    const float* c1_adst = (const float*)d_in[14];
    const float* c1_b    = (const float*)d_in[15];
    const float* c2_w    = (const float*)d_in[16];
    const float* c2_asrc = (const float*)d_in[17];
    const float* c2_adst = (const float*)d_in[18];
    const float* c2_b    = (const float*)d_in[19];
    const float* fc1_w   = (const float*)d_in[20];
    const float* fc1_b   = (const float*)d_in[21];
    const float* fc2_w   = (const float*)d_in[22];
    const float* fc2_b   = (const float*)d_in[23];
    float* out = (float*)d_out;

    // workspace carve (256B aligned)
    char* ws = (char*)d_ws;
    size_t off = 0;
    auto alloc = [&](size_t bytes) -> void* {
        off = (off + 255) & ~(size_t)255;
        void* p = ws + off;
        off += bytes;
        return p;
    };
    unsigned* counts  = (unsigned*)alloc(sizeof(unsigned) * N_NODES);
    unsigned* row_ptr = (unsigned*)alloc(sizeof(unsigned) * (N_NODES + 1));
    unsigned* cursor  = (unsigned*)alloc(sizeof(unsigned) * N_NODES);
    int*      csr_src = (int*)alloc(sizeof(int) * E_TOT);
    float*    hA      = (float*)alloc(sizeof(float) * (size_t)N_NODES * 64);
    float*    hL      = (float*)alloc(sizeof(float) * (size_t)N_NODES * 64);
    float*    hB      = (float*)alloc(sizeof(float) * (size_t)N_NODES * 64);
    float*    asrc    = (float*)alloc(sizeof(float) * N_NODES);
    float*    adst    = (float*)alloc(sizeof(float) * N_NODES);
    unsigned* g_enc   = (unsigned*)alloc(sizeof(unsigned) * N_GRAPHS * HIDDEN);

    const int blocks4 = (N_NODES + 3) / 4;          // wave-per-node kernels
    const int blocksE = (E_TOT + 255) / 256;        // edge kernels
    const int blocksZ = (N_NODES + 255) / 256;

    // CSR build (same graph used by both conv layers)
    zero_u32<<<blocksZ, 256, 0, stream>>>(counts, N_NODES);
    count_dst<<<blocksE, 256, 0, stream>>>(ei, counts);
    scan_counts<<<1, 1024, 0, stream>>>(counts, row_ptr, cursor);
    fill_csr<<<blocksE, 256, 0, stream>>>(ei, cursor, csr_src);

    // node embedding
    node_mlp<<<blocks4, 256, 0, stream>>>(x, n_w1, n_b1, n_w2, n_b2, hA);

    // GAT layer 1 (+ relu)
    gemm_alpha<<<blocks4, 256, 0, stream>>>(hA, c1_w, c1_asrc, c1_adst, hL, asrc, adst);
    gat_agg<1><<<blocks4, 256, 0, stream>>>(hL, asrc, adst, row_ptr, csr_src, c1_b, hB);

    // GAT layer 2 (no relu)
    gemm_alpha<<<blocks4, 256, 0, stream>>>(hB, c2_w, c2_asrc, c2_adst, hL, asrc, adst);
    gat_agg<0><<<blocks4, 256, 0, stream>>>(hL, asrc, adst, row_ptr, csr_src, c2_b, hA);

    // global max pool + readout MLP
    pool_init<<<(N_GRAPHS * HIDDEN + 255) / 256, 256, 0, stream>>>(g_enc);
    pool_max<<<blocks4, 256, 0, stream>>>(hA, batch, g_enc);
    readout<<<1, 128, 0, stream>>>(g_enc, fc1_w, fc1_b, fc2_w, fc2_b, out);
}

// Round 2
// 551.053 us; speedup vs baseline: 1.5505x; 1.5505x over previous
//
#include <hip/hip_runtime.h>
#include <hip/hip_fp16.h>
#include <math.h>

#define N_NODES   50000
#define N_EDGES   1600000
#define E_TOT     (N_EDGES + N_NODES)
#define N_FEAT    128
#define HIDDEN    64
#define N_GRAPHS  128
#define NEG_SLOPE 0.2f
#define NB_SCAN   ((N_NODES + 1023) / 1024)

// ---- monotone float<->uint encoding for atomicMax on floats ----
__device__ __forceinline__ unsigned fenc(float f) {
    unsigned u = __float_as_uint(f);
    return (u & 0x80000000u) ? ~u : (u | 0x80000000u);
}
__device__ __forceinline__ float fdec(unsigned k) {
    unsigned u = (k & 0x80000000u) ? (k & 0x7FFFFFFFu) : ~k;
    return __uint_as_float(u);
}

// ---- CSR build: count incoming edges per dst ----
__global__ void count_dst(const int* __restrict__ ei, unsigned* __restrict__ counts) {
    int e = blockIdx.x * 256 + threadIdx.x;
    if (e >= E_TOT) return;
    int dst = (e < N_EDGES) ? ei[N_EDGES + e] : (e - N_EDGES);
    atomicAdd(&counts[dst], 1u);
}

// ---- two-level scan: block-local exclusive scan + block totals ----
__global__ __launch_bounds__(1024) void scan_block(
    const unsigned* __restrict__ counts,
    unsigned* __restrict__ excl, unsigned* __restrict__ partial)
{
    __shared__ unsigned wt[16], wo[16];
    int tid = threadIdx.x, lane = tid & 63, wid = tid >> 6;
    int i = blockIdx.x * 1024 + tid;
    unsigned v = (i < N_NODES) ? counts[i] : 0u;
    unsigned xs = v;
#pragma unroll
    for (int off = 1; off < 64; off <<= 1) {
        unsigned t = __shfl_up(xs, off, 64);
        if (lane >= off) xs += t;
    }
    if (lane == 63) wt[wid] = xs;
    __syncthreads();
    if (tid == 0) {
        unsigned run = 0;
        for (int w = 0; w < 16; ++w) { wo[w] = run; run += wt[w]; }
        partial[blockIdx.x] = run;
    }
    __syncthreads();
    if (i < N_NODES) excl[i] = wo[wid] + xs - v;
}

__global__ void scan_partials(unsigned* partial) {
    if (threadIdx.x == 0) {
        unsigned run = 0;
        for (int b = 0; b < NB_SCAN; ++b) { unsigned t = partial[b]; partial[b] = run; run += t; }
    }
}

__global__ void scan_add(const unsigned* __restrict__ excl, const unsigned* __restrict__ partial,
                         unsigned* __restrict__ row_ptr, unsigned* __restrict__ cursor) {
    int i = blockIdx.x * 256 + threadIdx.x;
    if (i < N_NODES) {
        unsigned r = excl[i] + partial[i >> 10];
        row_ptr[i] = r;
        cursor[i]  = r;
    }
    if (i == 0) row_ptr[N_NODES] = E_TOT;
}

// ---- CSR fill: scatter src ids grouped by dst ----
__global__ void fill_csr(const int* __restrict__ ei,
                         unsigned* __restrict__ cursor, int* __restrict__ csr_src) {
    int e = blockIdx.x * 256 + threadIdx.x;
    if (e >= E_TOT) return;
    int src, dst;
    if (e < N_EDGES) { src = ei[e]; dst = ei[N_EDGES + e]; }
    else             { src = dst = e - N_EDGES; }
    unsigned pos = atomicAdd(&cursor[dst], 1u);
    csr_src[pos] = src;
}

// ---- fused: node MLP embedding + layer1 linear + alpha dots ----
__global__ __launch_bounds__(256) void embed_gemm1(
    const float* __restrict__ x,
    const float* __restrict__ n_w1, const float* __restrict__ n_b1,
    const float* __restrict__ n_w2, const float* __restrict__ n_b2,
    const float* __restrict__ c1w, const float* __restrict__ a1s, const float* __restrict__ a1d,
    __half* __restrict__ hlin, float* __restrict__ asrc, float* __restrict__ adst)
{
    __shared__ float xs[4 * N_FEAT];
    int tid = threadIdx.x;
    const float2* xp = (const float2*)(x + (size_t)blockIdx.x * 4 * N_FEAT);
    ((float2*)xs)[tid] = xp[tid];   // 4 rows, coalesced
    __syncthreads();
    int lane = tid & 63, w = tid >> 6;
    int n = blockIdx.x * 4 + w;
    const float* xr = xs + w * N_FEAT;
    float acc = n_b1[lane];
#pragma unroll 8
    for (int k = 0; k < N_FEAT; ++k)
        acc = fmaf(xr[k], n_w1[k * 64 + lane], acc);
    float h1 = fmaxf(acc, 0.f);
    float h2 = n_b2[lane];
#pragma unroll 8
    for (int k = 0; k < 64; ++k)
        h2 = fmaf(__shfl(h1, k, 64), n_w2[k * 64 + lane], h2);
    // layer-1 linear
    float hl = 0.f;
#pragma unroll 8
    for (int k = 0; k < 64; ++k)
        hl = fmaf(__shfl(h2, k, 64), c1w[k * 64 + lane], hl);
    hlin[(size_t)n * 64 + lane] = __float2half(hl);
    float ps = hl * a1s[lane], pd = hl * a1d[lane];
#pragma unroll
    for (int off = 32; off; off >>= 1) {
        ps += __shfl_xor(ps, off, 64);
        pd += __shfl_xor(pd, off, 64);
    }
    if (lane == 0) { asrc[n] = ps; adst[n] = pd; }
}

// ---- fused: GAT layer1 aggregate (+relu) + layer2 linear + alpha dots ----
__global__ __launch_bounds__(256) void agg1_gemm2(
    const __half* __restrict__ hlin1,
    const float* __restrict__ asrc, const float* __restrict__ adst,
    const unsigned* __restrict__ row_ptr, const int* __restrict__ csr_src,
    const float* __restrict__ c1b,
    const float* __restrict__ c2w, const float* __restrict__ a2s, const float* __restrict__ a2d,
    __half* __restrict__ hlin2, float* __restrict__ asrc2, float* __restrict__ adst2)
{
    int lane = threadIdx.x & 63;
    int d = blockIdx.x * 4 + (threadIdx.x >> 6);
    int s0 = (int)row_ptr[d], s1 = (int)row_ptr[d + 1];
    float ad = adst[d];
    // pass A: online softmax stats, lanes stride edges (coalesced, L2-hot)
    float m = -INFINITY, s = 0.f;
    for (int i = s0 + lane; i < s1; i += 64) {
        float e = asrc[csr_src[i]] + ad;
        e = (e >= 0.f) ? e : NEG_SLOPE * e;
        float mn = fmaxf(m, e);
        s = s * __expf(m - mn) + __expf(e - mn);
        m = mn;
    }
    float M = m;
#pragma unroll
    for (int off = 32; off; off >>= 1) M = fmaxf(M, __shfl_xor(M, off, 64));
    float sp = (m == -INFINITY) ? 0.f : s * __expf(m - M);
#pragma unroll
    for (int off = 32; off; off >>= 1) sp += __shfl_xor(sp, off, 64);
    float inv = 1.f / (sp + 1e-16f);
    // pass B: chunked — lane-parallel idx+weight, shfl-broadcast, gather fp16 rows
    float acc = 0.f;
    for (int base = s0; base < s1; base += 64) {
        int i = base + lane;
        int idx = 0; float wgt = 0.f;
        if (i < s1) {
            idx = csr_src[i];
            float e = asrc[idx] + ad;
            e = (e >= 0.f) ? e : NEG_SLOPE * e;
            wgt = __expf(e - M);
        }
        int cnt = min(64, s1 - base);
#pragma unroll 4
        for (int j = 0; j < cnt; ++j) {
            int sn = __shfl(idx, j, 64);
            float wj = __shfl(wgt, j, 64);
            acc = fmaf(wj, __half2float(hlin1[(size_t)sn * 64 + lane]), acc);
        }
    }
    float v = fmaxf(acc * inv + c1b[lane], 0.f);    // + bias, relu
    // layer-2 linear
    float hl = 0.f;
#pragma unroll 8
    for (int k = 0; k < 64; ++k)
        hl = fmaf(__shfl(v, k, 64), c2w[k * 64 + lane], hl);
    hlin2[(size_t)d * 64 + lane] = __float2half(hl);
    float ps = hl * a2s[lane], pd = hl * a2d[lane];
#pragma unroll
    for (int off = 32; off; off >>= 1) {
        ps += __shfl_xor(ps, off, 64);
        pd += __shfl_xor(pd, off, 64);
    }
    if (lane == 0) { asrc2[d] = ps; adst2[d] = pd; }
}

// ---- fused: GAT layer2 aggregate + bias + global max pool ----
__global__ __launch_bounds__(256) void agg2_pool(
    const __half* __restrict__ hlin2,
    const float* __restrict__ asrc, const float* __restrict__ adst,
    const unsigned* __restrict__ row_ptr, const int* __restrict__ csr_src,
    const float* __restrict__ c2b, const int* __restrict__ batch,
    unsigned* __restrict__ g_enc)
{
    int lane = threadIdx.x & 63;
    int d = blockIdx.x * 4 + (threadIdx.x >> 6);
    int s0 = (int)row_ptr[d], s1 = (int)row_ptr[d + 1];
    float ad = adst[d];
    float m = -INFINITY, s = 0.f;
    for (int i = s0 + lane; i < s1; i += 64) {
        float e = asrc[csr_src[i]] + ad;
        e = (e >= 0.f) ? e : NEG_SLOPE * e;
        float mn = fmaxf(m, e);
        s = s * __expf(m - mn) + __expf(e - mn);
        m = mn;
    }
    float M = m;
#pragma unroll
    for (int off = 32; off; off >>= 1) M = fmaxf(M, __shfl_xor(M, off, 64));
    float sp = (m == -INFINITY) ? 0.f : s * __expf(m - M);
#pragma unroll
    for (int off = 32; off; off >>= 1) sp += __shfl_xor(sp, off, 64);
    float inv = 1.f / (sp + 1e-16f);
    float acc = 0.f;
    for (int base = s0; base < s1; base += 64) {
        int i = base + lane;
        int idx = 0; float wgt = 0.f;
        if (i < s1) {
            idx = csr_src[i];
            float e = asrc[idx] + ad;
            e = (e >= 0.f) ? e : NEG_SLOPE * e;
            wgt = __expf(e - M);
        }
        int cnt = min(64, s1 - base);
#pragma unroll 4
        for (int j = 0; j < cnt; ++j) {
            int sn = __shfl(idx, j, 64);
            float wj = __shfl(wgt, j, 64);
            acc = fmaf(wj, __half2float(hlin2[(size_t)sn * 64 + lane]), acc);
        }
    }
    float v = acc * inv + c2b[lane];                // no relu
    atomicMax(&g_enc[batch[d] * 64 + lane], fenc(v));
}

// ---- global max pool init ----
__global__ void pool_init(unsigned* g_enc) {
    int i = blockIdx.x * 256 + threadIdx.x;
    if (i < N_GRAPHS * HIDDEN) g_enc[i] = fenc(-INFINITY);
}

// ---- readout MLP: wave per graph ----
__global__ __launch_bounds__(256) void readout(
    const unsigned* __restrict__ g_enc,
    const float* __restrict__ fc1w, const float* __restrict__ fc1b,
    const float* __restrict__ fc2w, const float* __restrict__ fc2b,
    float* __restrict__ out)
{
    int lane = threadIdx.x & 63;
    int gi = blockIdx.x * 4 + (threadIdx.x >> 6);
    float gv = fdec(g_enc[gi * 64 + lane]);
    float a = fc1b[lane];
#pragma unroll 8
    for (int k = 0; k < 64; ++k)
        a = fmaf(__shfl(gv, k, 64), fc1w[k * 64 + lane], a);
    a = fmaxf(a, 0.f) * fc2w[lane];
#pragma unroll
    for (int off = 32; off; off >>= 1) a += __shfl_xor(a, off, 64);
    if (lane == 0) out[gi] = a + fc2b[0];
}

extern "C" void kernel_launch(void* const* d_in, const int* in_sizes, int n_in,
                              void* d_out, int out_size, void* d_ws, size_t ws_size,
                              hipStream_t stream)
{
    const float* x      = (const float*)d_in[0];
    const int*   ei     = (const int*)d_in[1];
    // d_in[2] edge_attr: dead value in reference, never read
    const int*   batch  = (const int*)d_in[3];
    const float* n_w1   = (const float*)d_in[4];
    const float* n_b1   = (const float*)d_in[5];
    const float* n_w2   = (const float*)d_in[6];
    const float* n_b2   = (const float*)d_in[7];
    // d_in[8..11] edge MLP weights: dead
    const float* c1_w    = (const float*)d_in[12];
    const float* c1_asrc = (const float*)d_in[13];
    const float* c1_adst = (const float*)d_in[14];
    const float* c1_b    = (const float*)d_in[15];
    const float* c2_w    = (const float*)d_in[16];
    const float* c2_asrc = (const float*)d_in[17];
    const float* c2_adst = (const float*)d_in[18];
    const float* c2_b    = (const float*)d_in[19];
    const float* fc1_w   = (const float*)d_in[20];
    const float* fc1_b   = (const float*)d_in[21];
    const float* fc2_w   = (const float*)d_in[22];
    const float* fc2_b   = (const float*)d_in[23];
    float* out = (float*)d_out;

    // workspace carve (256B aligned)
    char* ws = (char*)d_ws;
    size_t off = 0;
    auto alloc = [&](size_t bytes) -> void* {
        off = (off + 255) & ~(size_t)255;
        void* p = ws + off;
        off += bytes;
        return p;
    };
    unsigned* counts  = (unsigned*)alloc(sizeof(unsigned) * N_NODES);
    unsigned* excl    = (unsigned*)alloc(sizeof(unsigned) * N_NODES);
    unsigned* partial = (unsigned*)alloc(sizeof(unsigned) * (NB_SCAN + 1));
    unsigned* row_ptr = (unsigned*)alloc(sizeof(unsigned) * (N_NODES + 1));
    unsigned* cursor  = (unsigned*)alloc(sizeof(unsigned) * N_NODES);
    int*      csr_src = (int*)alloc(sizeof(int) * E_TOT);
    __half*   hlin1   = (__half*)alloc(sizeof(__half) * (size_t)N_NODES * 64);
    __half*   hlin2   = (__half*)alloc(sizeof(__half) * (size_t)N_NODES * 64);
    float*    asrc1   = (float*)alloc(sizeof(float) * N_NODES);
    float*    adst1   = (float*)alloc(sizeof(float) * N_NODES);
    float*    asrc2   = (float*)alloc(sizeof(float) * N_NODES);
    float*    adst2   = (float*)alloc(sizeof(float) * N_NODES);
    unsigned* g_enc   = (unsigned*)alloc(sizeof(unsigned) * N_GRAPHS * HIDDEN);

    const int blocks4 = N_NODES / 4;          // 12500, exact
    const int blocksE = (E_TOT + 255) / 256;

    // CSR build
    hipMemsetAsync(counts, 0, sizeof(unsigned) * N_NODES, stream);
    count_dst<<<blocksE, 256, 0, stream>>>(ei, counts);
    scan_block<<<NB_SCAN, 1024, 0, stream>>>(counts, excl, partial);
    scan_partials<<<1, 64, 0, stream>>>(partial);
    scan_add<<<(N_NODES + 255) / 256, 256, 0, stream>>>(excl, partial, row_ptr, cursor);
    fill_csr<<<blocksE, 256, 0, stream>>>(ei, cursor, csr_src);

    // fused pipeline
    embed_gemm1<<<blocks4, 256, 0, stream>>>(x, n_w1, n_b1, n_w2, n_b2,
                                             c1_w, c1_asrc, c1_adst,
                                             hlin1, asrc1, adst1);
    agg1_gemm2<<<blocks4, 256, 0, stream>>>(hlin1, asrc1, adst1, row_ptr, csr_src,
                                            c1_b, c2_w, c2_asrc, c2_adst,
                                            hlin2, asrc2, adst2);
    pool_init<<<(N_GRAPHS * HIDDEN + 255) / 256, 256, 0, stream>>>(g_enc);
    agg2_pool<<<blocks4, 256, 0, stream>>>(hlin2, asrc2, adst2, row_ptr, csr_src,
                                           c2_b, batch, g_enc);
    readout<<<N_GRAPHS / 4, 256, 0, stream>>>(g_enc, fc1_w, fc1_b, fc2_w, fc2_b, out);
}

// Round 3
// 441.796 us; speedup vs baseline: 1.9339x; 1.2473x over previous
//
#include <hip/hip_runtime.h>
#include <hip/hip_fp16.h>
#include <math.h>

#define N_NODES   50000
#define N_EDGES   1600000
#define E_TOT     (N_EDGES + N_NODES)
#define N_FEAT    128
#define HIDDEN    64
#define N_GRAPHS  128
#define NEG_SLOPE 0.2f
#define NB_SCAN   ((N_NODES + 1023) / 1024)
#define OCT_N     (N_NODES / 8)          // 6250, exact
#define FB_GRP    96                      // edge-slices per octant
#define FB_CE     ((E_TOT + FB_GRP - 1) / FB_GRP)

// ---- monotone float<->uint encoding for atomicMax on floats ----
__device__ __forceinline__ unsigned fenc(float f) {
    unsigned u = __float_as_uint(f);
    return (u & 0x80000000u) ? ~u : (u | 0x80000000u);
}
__device__ __forceinline__ float fdec(unsigned k) {
    unsigned u = (k & 0x80000000u) ? (k & 0x7FFFFFFFu) : ~k;
    return __uint_as_float(u);
}

// ---- CSR build: count incoming edges per dst ----
__global__ void count_dst(const int* __restrict__ ei, unsigned* __restrict__ counts) {
    int e = blockIdx.x * 256 + threadIdx.x;
    if (e >= E_TOT) return;
    int dst = (e < N_EDGES) ? ei[N_EDGES + e] : (e - N_EDGES);
    atomicAdd(&counts[dst], 1u);
}

// ---- two-level scan: block-local exclusive scan + block totals ----
__global__ __launch_bounds__(1024) void scan_block(
    const unsigned* __restrict__ counts,
    unsigned* __restrict__ excl, unsigned* __restrict__ partial)
{
    __shared__ unsigned wt[16], wo[16];
    int tid = threadIdx.x, lane = tid & 63, wid = tid >> 6;
    int i = blockIdx.x * 1024 + tid;
    unsigned v = (i < N_NODES) ? counts[i] : 0u;
    unsigned xs = v;
#pragma unroll
    for (int off = 1; off < 64; off <<= 1) {
        unsigned t = __shfl_up(xs, off, 64);
        if (lane >= off) xs += t;
    }
    if (lane == 63) wt[wid] = xs;
    __syncthreads();
    if (tid == 0) {
        unsigned run = 0;
        for (int w = 0; w < 16; ++w) { wo[w] = run; run += wt[w]; }
        partial[blockIdx.x] = run;
    }
    __syncthreads();
    if (i < N_NODES) excl[i] = wo[wid] + xs - v;
}

// ---- finalize: add scanned partials -> row_ptr & cursor; also init pool ----
__global__ __launch_bounds__(256) void scan_add(
    const unsigned* __restrict__ excl, const unsigned* __restrict__ partial,
    unsigned* __restrict__ row_ptr, unsigned* __restrict__ cursor,
    unsigned* __restrict__ g_enc)
{
    int tid = threadIdx.x, lane = tid & 63;
    int bg = blockIdx.x >> 2;                 // 1024-group index (uniform per block)
    unsigned pv = (lane < bg) ? partial[lane] : 0u;   // bg <= 48 < 64
#pragma unroll
    for (int off = 32; off; off >>= 1) pv += __shfl_xor(pv, off, 64);
    int i = blockIdx.x * 256 + tid;
    if (i < N_NODES) {
        unsigned r = excl[i] + pv;
        row_ptr[i] = r;
        cursor[i]  = r;
    }
    if (i == 0) row_ptr[N_NODES] = E_TOT;
    if (blockIdx.x == 0) {
        for (int j = tid; j < N_GRAPHS * HIDDEN; j += 256)
            g_enc[j] = fenc(-INFINITY);
    }
}

// ---- CSR fill, XCD-octant partitioned: blockIdx%8 -> XCD -> dst octant ----
__global__ __launch_bounds__(256) void fill_csr_oct(
    const int* __restrict__ ei,
    unsigned* __restrict__ cursor, int* __restrict__ csr_src)
{
    int oct = blockIdx.x & 7;        // round-robin XCD mapping
    int grp = blockIdx.x >> 3;       // edge-slice index
    int lo = oct * OCT_N, hi = lo + OCT_N;
    int beg = grp * FB_CE;
    int end = min(beg + FB_CE, E_TOT);
    for (int base = beg; base < end; base += 256) {
        int e = base + threadIdx.x;
        if (e < end) {
            int dst = (e < N_EDGES) ? ei[N_EDGES + e] : (e - N_EDGES);
            if (dst >= lo && dst < hi) {
                int src = (e < N_EDGES) ? ei[e] : dst;
                unsigned pos = atomicAdd(&cursor[dst], 1u);
                csr_src[pos] = src;
            }
        }
    }
}

// ---- fused: node MLP embedding + layer1 linear + alpha dots ----
__global__ __launch_bounds__(256) void embed_gemm1(
    const float* __restrict__ x,
    const float* __restrict__ n_w1, const float* __restrict__ n_b1,
    const float* __restrict__ n_w2, const float* __restrict__ n_b2,
    const float* __restrict__ c1w, const float* __restrict__ a1s, const float* __restrict__ a1d,
    __half* __restrict__ hlin, float* __restrict__ asrc, float* __restrict__ adst)
{
    __shared__ float xs[4 * N_FEAT];
    int tid = threadIdx.x;
    const float2* xp = (const float2*)(x + (size_t)blockIdx.x * 4 * N_FEAT);
    ((float2*)xs)[tid] = xp[tid];   // 4 rows, coalesced
    __syncthreads();
    int lane = tid & 63, w = tid >> 6;
    int n = blockIdx.x * 4 + w;
    const float* xr = xs + w * N_FEAT;
    float acc = n_b1[lane];
#pragma unroll 8
    for (int k = 0; k < N_FEAT; ++k)
        acc = fmaf(xr[k], n_w1[k * 64 + lane], acc);
    float h1 = fmaxf(acc, 0.f);
    float h2 = n_b2[lane];
#pragma unroll 8
    for (int k = 0; k < 64; ++k)
        h2 = fmaf(__shfl(h1, k, 64), n_w2[k * 64 + lane], h2);
    float hl = 0.f;
#pragma unroll 8
    for (int k = 0; k < 64; ++k)
        hl = fmaf(__shfl(h2, k, 64), c1w[k * 64 + lane], hl);
    hlin[(size_t)n * 64 + lane] = __float2half(hl);
    float ps = hl * a1s[lane], pd = hl * a1d[lane];
#pragma unroll
    for (int off = 32; off; off >>= 1) {
        ps += __shfl_xor(ps, off, 64);
        pd += __shfl_xor(pd, off, 64);
    }
    if (lane == 0) { asrc[n] = ps; adst[n] = pd; }
}

// ---- softmax stats helper: online max/sum over a dst's edge list ----
__device__ __forceinline__ void softmax_stats(
    const float* __restrict__ asrc, const int* __restrict__ csr_src,
    int s0, int s1, float ad, int lane, float& M, float& inv)
{
    float m = -INFINITY, s = 0.f;
    for (int i = s0 + lane; i < s1; i += 64) {
        float e = asrc[csr_src[i]] + ad;
        e = (e >= 0.f) ? e : NEG_SLOPE * e;
        float mn = fmaxf(m, e);
        s = s * __expf(m - mn) + __expf(e - mn);
        m = mn;
    }
    M = m;
#pragma unroll
    for (int off = 32; off; off >>= 1) M = fmaxf(M, __shfl_xor(M, off, 64));
    float sp = (m == -INFINITY) ? 0.f : s * __expf(m - M);
#pragma unroll
    for (int off = 32; off; off >>= 1) sp += __shfl_xor(sp, off, 64);
    inv = 1.f / (sp + 1e-16f);
}

// ---- weighted gather: acc = sum alpha_unnorm * h[src][lane], dual-acc ILP ----
__device__ __forceinline__ float gather_agg(
    const __half* __restrict__ hmat, const float* __restrict__ asrc,
    const int* __restrict__ csr_src, int s0, int s1, float ad, float M, int lane)
{
    float acc0 = 0.f, acc1 = 0.f;
    for (int base = s0; base < s1; base += 64) {
        int i = base + lane;
        int idx = 0; float wgt = 0.f;
        if (i < s1) {
            idx = csr_src[i];
            float e = asrc[idx] + ad;
            e = (e >= 0.f) ? e : NEG_SLOPE * e;
            wgt = __expf(e - M);
        }
        int cnt = min(64, s1 - base);
        int j = 0;
#pragma unroll 4
        for (; j + 1 < cnt; j += 2) {
            int sn0 = __shfl(idx, j, 64);     float w0 = __shfl(wgt, j, 64);
            int sn1 = __shfl(idx, j + 1, 64); float w1 = __shfl(wgt, j + 1, 64);
            acc0 = fmaf(w0, __half2float(hmat[(size_t)sn0 * 64 + lane]), acc0);
            acc1 = fmaf(w1, __half2float(hmat[(size_t)sn1 * 64 + lane]), acc1);
        }
        if (j < cnt) {
            int sn = __shfl(idx, j, 64); float wj = __shfl(wgt, j, 64);
            acc0 = fmaf(wj, __half2float(hmat[(size_t)sn * 64 + lane]), acc0);
        }
    }
    return acc0 + acc1;
}

// ---- fused: GAT layer1 aggregate (+relu) + layer2 linear + alpha dots ----
__global__ __launch_bounds__(256) void agg1_gemm2(
    const __half* __restrict__ hlin1,
    const float* __restrict__ asrc, const float* __restrict__ adst,
    const unsigned* __restrict__ row_ptr, const int* __restrict__ csr_src,
    const float* __restrict__ c1b,
    const float* __restrict__ c2w, const float* __restrict__ a2s, const float* __restrict__ a2d,
    __half* __restrict__ hlin2, float* __restrict__ asrc2, float* __restrict__ adst2)
{
    int lane = threadIdx.x & 63;
    int d = blockIdx.x * 4 + (threadIdx.x >> 6);
    int s0 = (int)row_ptr[d], s1 = (int)row_ptr[d + 1];
    float ad = adst[d];
    float M, inv;
    softmax_stats(asrc, csr_src, s0, s1, ad, lane, M, inv);
    float acc = gather_agg(hlin1, asrc, csr_src, s0, s1, ad, M, lane);
    float v = fmaxf(acc * inv + c1b[lane], 0.f);    // + bias, relu
    float hl = 0.f;
#pragma unroll 8
    for (int k = 0; k < 64; ++k)
        hl = fmaf(__shfl(v, k, 64), c2w[k * 64 + lane], hl);
    hlin2[(size_t)d * 64 + lane] = __float2half(hl);
    float ps = hl * a2s[lane], pd = hl * a2d[lane];
#pragma unroll
    for (int off = 32; off; off >>= 1) {
        ps += __shfl_xor(ps, off, 64);
        pd += __shfl_xor(pd, off, 64);
    }
    if (lane == 0) { asrc2[d] = ps; adst2[d] = pd; }
}

// ---- fused: GAT layer2 aggregate + bias + global max pool ----
__global__ __launch_bounds__(256) void agg2_pool(
    const __half* __restrict__ hlin2,
    const float* __restrict__ asrc, const float* __restrict__ adst,
    const unsigned* __restrict__ row_ptr, const int* __restrict__ csr_src,
    const float* __restrict__ c2b, const int* __restrict__ batch,
    unsigned* __restrict__ g_enc)
{
    int lane = threadIdx.x & 63;
    int d = blockIdx.x * 4 + (threadIdx.x >> 6);
    int s0 = (int)row_ptr[d], s1 = (int)row_ptr[d + 1];
    float ad = adst[d];
    float M, inv;
    softmax_stats(asrc, csr_src, s0, s1, ad, lane, M, inv);
    float acc = gather_agg(hlin2, asrc, csr_src, s0, s1, ad, M, lane);
    float v = acc * inv + c2b[lane];                // no relu
    atomicMax(&g_enc[batch[d] * 64 + lane], fenc(v));
}

// ---- readout MLP: wave per graph ----
__global__ __launch_bounds__(256) void readout(
    const unsigned* __restrict__ g_enc,
    const float* __restrict__ fc1w, const float* __restrict__ fc1b,
    const float* __restrict__ fc2w, const float* __restrict__ fc2b,
    float* __restrict__ out)
{
    int lane = threadIdx.x & 63;
    int gi = blockIdx.x * 4 + (threadIdx.x >> 6);
    float gv = fdec(g_enc[gi * 64 + lane]);
    float a = fc1b[lane];
#pragma unroll 8
    for (int k = 0; k < 64; ++k)
        a = fmaf(__shfl(gv, k, 64), fc1w[k * 64 + lane], a);
    a = fmaxf(a, 0.f) * fc2w[lane];
#pragma unroll
    for (int off = 32; off; off >>= 1) a += __shfl_xor(a, off, 64);
    if (lane == 0) out[gi] = a + fc2b[0];
}

extern "C" void kernel_launch(void* const* d_in, const int* in_sizes, int n_in,
                              void* d_out, int out_size, void* d_ws, size_t ws_size,
                              hipStream_t stream)
{
    const float* x      = (const float*)d_in[0];
    const int*   ei     = (const int*)d_in[1];
    // d_in[2] edge_attr: dead value in reference, never read
    const int*   batch  = (const int*)d_in[3];
    const float* n_w1   = (const float*)d_in[4];
    const float* n_b1   = (const float*)d_in[5];
    const float* n_w2   = (const float*)d_in[6];
    const float* n_b2   = (const float*)d_in[7];
    // d_in[8..11] edge MLP weights: dead
    const float* c1_w    = (const float*)d_in[12];
    const float* c1_asrc = (const float*)d_in[13];
    const float* c1_adst = (const float*)d_in[14];
    const float* c1_b    = (const float*)d_in[15];
    const float* c2_w    = (const float*)d_in[16];
    const float* c2_asrc = (const float*)d_in[17];
    const float* c2_adst = (const float*)d_in[18];
    const float* c2_b    = (const float*)d_in[19];
    const float* fc1_w   = (const float*)d_in[20];
    const float* fc1_b   = (const float*)d_in[21];
    const float* fc2_w   = (const float*)d_in[22];
    const float* fc2_b   = (const float*)d_in[23];
    float* out = (float*)d_out;

    // workspace carve (256B aligned)
    char* ws = (char*)d_ws;
    size_t off = 0;
    auto alloc = [&](size_t bytes) -> void* {
        off = (off + 255) & ~(size_t)255;
        void* p = ws + off;
        off += bytes;
        return p;
    };
    unsigned* counts  = (unsigned*)alloc(sizeof(unsigned) * N_NODES);
    unsigned* excl    = (unsigned*)alloc(sizeof(unsigned) * N_NODES);
    unsigned* partial = (unsigned*)alloc(sizeof(unsigned) * (NB_SCAN + 1));
    unsigned* row_ptr = (unsigned*)alloc(sizeof(unsigned) * (N_NODES + 1));
    unsigned* cursor  = (unsigned*)alloc(sizeof(unsigned) * N_NODES);
    int*      csr_src = (int*)alloc(sizeof(int) * E_TOT);
    __half*   hlin1   = (__half*)alloc(sizeof(__half) * (size_t)N_NODES * 64);
    __half*   hlin2   = (__half*)alloc(sizeof(__half) * (size_t)N_NODES * 64);
    float*    asrc1   = (float*)alloc(sizeof(float) * N_NODES);
    float*    adst1   = (float*)alloc(sizeof(float) * N_NODES);
    float*    asrc2   = (float*)alloc(sizeof(float) * N_NODES);
    float*    adst2   = (float*)alloc(sizeof(float) * N_NODES);
    unsigned* g_enc   = (unsigned*)alloc(sizeof(unsigned) * N_GRAPHS * HIDDEN);

    const int blocks4 = N_NODES / 4;          // 12500, exact
    const int blocksE = (E_TOT + 255) / 256;

    // CSR build
    hipMemsetAsync(counts, 0, sizeof(unsigned) * N_NODES, stream);
    count_dst<<<blocksE, 256, 0, stream>>>(ei, counts);
    scan_block<<<NB_SCAN, 1024, 0, stream>>>(counts, excl, partial);
    scan_add<<<(N_NODES + 255) / 256, 256, 0, stream>>>(excl, partial, row_ptr, cursor, g_enc);
    fill_csr_oct<<<8 * FB_GRP, 256, 0, stream>>>(ei, cursor, csr_src);

    // fused pipeline
    embed_gemm1<<<blocks4, 256, 0, stream>>>(x, n_w1, n_b1, n_w2, n_b2,
                                             c1_w, c1_asrc, c1_adst,
                                             hlin1, asrc1, adst1);
    agg1_gemm2<<<blocks4, 256, 0, stream>>>(hlin1, asrc1, adst1, row_ptr, csr_src,
                                            c1_b, c2_w, c2_asrc, c2_adst,
                                            hlin2, asrc2, adst2);
    agg2_pool<<<blocks4, 256, 0, stream>>>(hlin2, asrc2, adst2, row_ptr, csr_src,
                                           c2_b, batch, g_enc);
    readout<<<N_GRAPHS / 4, 256, 0, stream>>>(g_enc, fc1_w, fc1_b, fc2_w, fc2_b, out);
}